// Round 13
// baseline (497.264 us; speedup 1.0000x reference)
//
#include <hip/hip_runtime.h>
#include <hip/hip_bf16.h>

typedef __bf16 bf16x8 __attribute__((ext_vector_type(8)));
typedef __bf16 bf16x4 __attribute__((ext_vector_type(4)));
typedef float floatx4 __attribute__((ext_vector_type(4)));

static constexpr int BB = 8;      // batch
static constexpr int NN = 1024;   // nodes
static constexpr int FF = 128;    // features
static constexpr int NT = 12;     // attention tasks: 0-5 rel, 6-8 fwd, 9-11 bwd

// workspace layout (bytes)
static constexpr size_t H_OFF  = 0;                                   // bf16 H^T [8][12][128][1024]
static constexpr size_t H_SZ   = (size_t)BB*NT*FF*NN*2;
static constexpr size_t EL_OFF = H_OFF + H_SZ;                        // f32 [96][1024]
static constexpr size_t EL_SZ  = (size_t)BB*NT*NN*4;
static constexpr size_t ER_OFF = EL_OFF + EL_SZ;                      // f32 [96][1024]
static constexpr size_t DV_OFF = ER_OFF + EL_SZ;                      // f32 [8][3][1024]
static constexpr size_t DV_SZ  = (size_t)BB*3*NN*4;
static constexpr size_t FV_OFF = DV_OFF + DV_SZ;                      // f32 folded [128][128] (rows 24+ zero)
static constexpr size_t FV_SZ  = (size_t)128*128*4;
static constexpr size_t FB_OFF = FV_OFF + FV_SZ;                      // f32 folded bias [128]
static constexpr size_t XL_OFF = FB_OFF + 512;                        // f32 exp(el) [96][1024]
static constexpr size_t XR_OFF = XL_OFF + EL_SZ;                      // f32 exp(er) [96][1024]

__device__ __forceinline__ unsigned short f2bf(float f) {
    union { float f; unsigned int i; } c; c.f = f;
    unsigned int r = (c.i + 0x7fffu + ((c.i >> 16) & 1u)) >> 16;   // RNE, finite inputs
    return (unsigned short)r;
}
// pack two positive floats to bf16x2 (round-half-up, 4 ops) — k5 hot path
__device__ __forceinline__ unsigned int pk2bf(float lo, float hi) {
    unsigned int il = __float_as_uint(lo) + 0x8000u;
    unsigned int ih = __float_as_uint(hi) + 0x8000u;
    return (il >> 16) | (ih & 0xffff0000u);
}

// ---------------------------------------------------------------------------
// K0: setup. Blocks 0..127: folded attention vectors FV[v][k] (v=2t+side,
// rows 24..127 zeroed) + folded biases FB[v]. Blocks 128..223: diag extract.
// ---------------------------------------------------------------------------
__global__ __launch_bounds__(256) void k0_setup(
    const float* __restrict__ adjs, const float* __restrict__ fc_w,
    const float* __restrict__ fc_b,
    const float* __restrict__ att_w, const float* __restrict__ att_b,
    const float* __restrict__ fwd_att_w, const float* __restrict__ fwd_att_b,
    const float* __restrict__ bwd_att_w, const float* __restrict__ bwd_att_b,
    float* __restrict__ FV, float* __restrict__ FB, float* __restrict__ DV)
{
    __shared__ float red[128];
    const int tid = threadIdx.x;
    const int bid = blockIdx.x;
    if (bid < 128) {
        const int v = bid;
        if (tid < 128) {
            float s = 0.f, bacc = 0.f;
            if (v < 24) {
                const int t = v >> 1, side = v & 1;
                const int hch = (t < 6) ? t : 5;
                const float* aw =
                    (t < 6) ? att_w + t * 256 :
                    (t < 9) ? fwd_att_w + (t - 6) * 256 : bwd_att_w + (t - 9) * 256;
                aw += side * 128;
                const float* W = fc_w + hch * 16384;
                for (int f = 0; f < 128; ++f) s += aw[f] * W[f * 128 + tid];
                bacc = fc_b[hch * 128 + tid] * aw[tid];
            }
            FV[v * 128 + tid] = s;
            red[tid] = bacc;
        }
        __syncthreads();
        if (tid == 0) {
            float s = 0.f;
            if (v < 24) {
                for (int i = 0; i < 128; ++i) s += red[i];
                if (v & 1) {
                    const int t = v >> 1;
                    s += (t < 6) ? att_b[t] : (t < 9) ? fwd_att_b[t - 6] : bwd_att_b[t - 9];
                }
            }
            FB[v] = s;
        }
    } else {
        const int gid = (bid - 128) * 256 + tid;   // (b*3+jj)*1024+n
        const int b   = gid / 3072;
        const int rem = gid % 3072;
        const int jj  = rem >> 10;
        const int n   = rem & 1023;
        DV[gid] = adjs[(((size_t)b * 9 + 3 + jj) * NN + n) * NN + n];
    }
}

// ---------------------------------------------------------------------------
// K1 v2: bf16 MFMA GEMM with 128-row x 128-col (full-channel) tiles.
// Grid (14, 64). ch0 -> d_out; ch 1..12 -> H^T bf16; ch13 -> el/er/exp.
// ---------------------------------------------------------------------------
__global__ __launch_bounds__(256) void k1_gemm(
    const float* __restrict__ x,
    const float* __restrict__ fc_w, const float* __restrict__ fc_b,
    const float* __restrict__ fwd_fc_w, const float* __restrict__ fwd_fc_b,
    const float* __restrict__ bwd_fc_w, const float* __restrict__ bwd_fc_b,
    const float* __restrict__ self_w, const float* __restrict__ self_b,
    const float* __restrict__ bias_in,
    const float* __restrict__ FV, const float* __restrict__ FB,
    float* __restrict__ out, unsigned short* __restrict__ H16T,
    float* __restrict__ el, float* __restrict__ er,
    float* __restrict__ xl, float* __restrict__ xr)
{
    __shared__ __align__(16) char smem[52224];
    __bf16* Als = (__bf16*)smem;                  // [128][136] = 34816 B
    __bf16* Bls = (__bf16*)(smem + 34816);        // [64][136]  = 17408 B

    const int tid = threadIdx.x;
    const int m0  = blockIdx.y * 128;      // global row (b*1024+n)
    const int ch  = blockIdx.x;            // channel 0..13

    const float* wsel; const float* bsel;
    if (ch == 0)       { wsel = self_w;                    bsel = self_b; }
    else if (ch <= 6)  { wsel = fc_w     + (ch-1)*16384;   bsel = fc_b     + (ch-1)*128; }
    else if (ch <= 9)  { wsel = fwd_fc_w + (ch-7)*16384;   bsel = fwd_fc_b + (ch-7)*128; }
    else if (ch <= 12) { wsel = bwd_fc_w + (ch-10)*16384;  bsel = bwd_fc_b + (ch-10)*128; }
    else               { wsel = FV;                        bsel = FB; }

    // stage A: 128 rows x 128 k (fp32 -> bf16)
    for (int it = 0; it < 16; ++it) {
        int idx = tid + it * 256;          // 4096 float4 slots
        int r  = idx >> 5;
        int c4 = idx & 31;
        float4 va = *reinterpret_cast<const float4*>(x + (size_t)(m0 + r) * 128 + c4 * 4);
        *reinterpret_cast<bf16x4*>(&Als[r * 136 + c4 * 4]) =
            (bf16x4){(__bf16)va.x, (__bf16)va.y, (__bf16)va.z, (__bf16)va.w};
    }

    const int wv   = tid >> 6;
    const int lane = tid & 63;
    const int lrow = lane & 15;
    const int quad = lane >> 4;

    floatx4 acc[2][8];
    #pragma unroll
    for (int mt = 0; mt < 2; ++mt)
        #pragma unroll
        for (int c = 0; c < 8; ++c) acc[mt][c] = (floatx4){0.f, 0.f, 0.f, 0.f};

    for (int half = 0; half < 2; ++half) {
        __syncthreads();   // half 0: A staged; half 1: previous B reads done
        for (int it = 0; it < 8; ++it) {
            int idx = tid + it * 256;      // 2048 float4 slots
            int r  = idx >> 5;
            int c4 = idx & 31;
            float4 vb = *reinterpret_cast<const float4*>(
                wsel + (size_t)(half * 64 + r) * 128 + c4 * 4);
            *reinterpret_cast<bf16x4*>(&Bls[r * 136 + c4 * 4]) =
                (bf16x4){(__bf16)vb.x, (__bf16)vb.y, (__bf16)vb.z, (__bf16)vb.w};
        }
        __syncthreads();

        #pragma unroll
        for (int kk = 0; kk < 4; ++kk) {
            const int k0 = kk * 32 + quad * 8;
            bf16x8 a0 = *reinterpret_cast<const bf16x8*>(&Als[(wv * 32 + lrow) * 136 + k0]);
            bf16x8 a1 = *reinterpret_cast<const bf16x8*>(&Als[(wv * 32 + 16 + lrow) * 136 + k0]);
            #pragma unroll
            for (int c = 0; c < 4; ++c) {
                bf16x8 bfr = *reinterpret_cast<const bf16x8*>(&Bls[(c * 16 + lrow) * 136 + k0]);
                acc[0][half * 4 + c] = __builtin_amdgcn_mfma_f32_16x16x32_bf16(a0, bfr, acc[0][half * 4 + c], 0, 0, 0);
                acc[1][half * 4 + c] = __builtin_amdgcn_mfma_f32_16x16x32_bf16(a1, bfr, acc[1][half * 4 + c], 0, 0, 0);
            }
        }
    }

    // ---- epilogue (reuses smem) ----
    __syncthreads();   // all MFMA LDS reads done

    const int b  = m0 >> 10;
    const int nb = m0 & 1023;

    if (ch >= 1 && ch <= 12) {
        // pack bf16 row-pairs into uint grid [fcol 0..127][rowpair 0..63], stride 65
        unsigned int* SDH = (unsigned int*)smem;   // 128*65*4 = 33280 B
        #pragma unroll
        for (int c = 0; c < 8; ++c) {
            const int fl = c * 16 + lrow;
            const float bv = bsel[fl];
            #pragma unroll
            for (int mt = 0; mt < 2; ++mt) {
                #pragma unroll
                for (int p = 0; p < 2; ++p) {
                    unsigned int pk = (unsigned int)f2bf(acc[mt][c][2*p] + bv)
                                    | ((unsigned int)f2bf(acc[mt][c][2*p+1] + bv) << 16);
                    SDH[fl * 65 + wv * 16 + mt * 8 + quad * 2 + p] = pk;
                }
            }
        }
        __syncthreads();
        const int f  = tid >> 1;               // 0..127
        const int ns = (tid & 1) * 64;         // shorts
        unsigned short* dst = H16T + (((size_t)b * NT + (ch - 1)) * FF + f) * NN + nb + ns;
        #pragma unroll
        for (int g = 0; g < 8; ++g) {
            const unsigned int* src = &SDH[f * 65 + ns / 2 + g * 4];
            *reinterpret_cast<uint4*>(dst + g * 8) = (uint4){src[0], src[1], src[2], src[3]};
        }
    } else if (ch == 0) {
        // two 64-col passes through SD [128][68] f32 (34816 B)
        float* SD = (float*)smem;
        #pragma unroll
        for (int half = 0; half < 2; ++half) {
            if (half) __syncthreads();
            #pragma unroll
            for (int c = 0; c < 4; ++c) {
                const int fl = c * 16 + lrow;
                const float bv = bsel[half * 64 + fl] + bias_in[half * 64 + fl];
                #pragma unroll
                for (int mt = 0; mt < 2; ++mt)
                    #pragma unroll
                    for (int r = 0; r < 4; ++r)
                        SD[(wv * 32 + mt * 16 + quad * 4 + r) * 68 + fl] = acc[mt][half * 4 + c][r] + bv;
            }
            __syncthreads();
            const int n  = tid >> 1;           // 0..127
            const int fs = (tid & 1) * 32;
            float* dst = out + (size_t)(m0 + n) * 128 + half * 64 + fs;
            #pragma unroll
            for (int g = 0; g < 8; ++g)
                reinterpret_cast<float4*>(dst)[g] =
                    *reinterpret_cast<const float4*>(&SD[n * 68 + fs + 4 * g]);
        }
    } else {
        // ch 13: only cols 0..23 meaningful -> single half-0 pass
        float* SD = (float*)smem;
        #pragma unroll
        for (int c = 0; c < 4; ++c) {
            const int fl = c * 16 + lrow;
            const float bv = bsel[fl];
            #pragma unroll
            for (int mt = 0; mt < 2; ++mt)
                #pragma unroll
                for (int r = 0; r < 4; ++r)
                    SD[(wv * 32 + mt * 16 + quad * 4 + r) * 68 + fl] = acc[mt][c][r] + bv;
        }
        __syncthreads();
        const int n  = tid >> 1;               // 0..127
        const int c3 = tid & 1;
        #pragma unroll
        for (int tt = 0; tt < 6; ++tt) {
            const int t = c3 * 6 + tt;
            const float ev = SD[n * 68 + 2 * t];
            const float rv = SD[n * 68 + 2 * t + 1];
            const size_t o = ((size_t)b * NT + t) * NN + nb + n;
            el[o] = ev;  xl[o] = __expf(ev);
            er[o] = rv;  xr[o] = __expf(rv);
        }
    }
}

// ---------------------------------------------------------------------------
// K5-dense v8: 64-row tiles, grid 1536 (6 blocks/CU vs R9's grid-limited 3).
// Per-wave state halves (single m-tile, acc 9x4) -> more resident waves to
// hide the ~900cyc adjacency-load latency. Same total MFMA/adjacency traffic.
//  q = max( exp(el_i)*exp(er_j)*a , fma(a, 0.01*(el_i+er_j), 1) ), a in {0,1}.
// ---------------------------------------------------------------------------
__global__ __launch_bounds__(256) void k5_dense(
    const float* __restrict__ adjs, const unsigned short* __restrict__ H16T,
    const float* __restrict__ el, const float* __restrict__ er,
    const float* __restrict__ xl, const float* __restrict__ xr,
    const float* __restrict__ dv, float* __restrict__ out)
{
    __shared__ __align__(16) unsigned short Hls[144][72];  // [f][j], rows 128+ = ones
    __shared__ float lls[64];

    const int tid  = threadIdx.x;
    const int lane = tid & 63;
    const int wv   = tid >> 6;
    const int bi   = blockIdx.x;
    const int b    = bi & 7;               // batch -> XCD
    const int q    = bi >> 3;              // 0..191
    const int tq   = q >> 4;               // 0..11 schedule slot
    // schedule {0..5,6,9,7,10,8,11}: fwd/bwd of same slab adjacent for L2 reuse
    const int t    = (tq < 6) ? tq : (6 + (tq - 6) / 2 + ((tq - 6) & 1) * 3);
    const int i0   = (q & 15) * 64;
    const int bt   = b * NT + t;

    const unsigned short* hb = H16T + (size_t)bt * FF * NN;
    const float* elp = el + (size_t)bt * NN;
    const float* erp = er + (size_t)bt * NN;
    const float* xrp = xr + (size_t)bt * NN;
    const float* dvp = dv + (size_t)(b * 3 + ((t - 3) % 3 + 3) % 3) * NN;

    int mode; const float* slab = nullptr;
    if (t < 3)       { mode = 0; slab = adjs + ((size_t)b * 9 + t) * (size_t)NN * NN; }
    else if (t < 6)  { mode = 1; }
    else if (t < 9)  { mode = 0; slab = adjs + ((size_t)b * 9 + t) * (size_t)NN * NN; }
    else             { mode = 2; slab = adjs + ((size_t)b * 9 + (t - 3)) * (size_t)NN * NN; }

    const int lrow = lane & 15;
    const int quad = lane >> 4;
    const int kq   = quad * 8;
    const int r0   = i0 + wv * 16 + lrow;

    const float c0  = 0.01f * elp[r0];     // negative-branch linear term
    const float Ei0 = xl[(size_t)bt * NN + r0];
    float gdv0 = 1.f;
    if (mode == 1) gdv0 = dvp[r0];         // exact 0/1

    // ones rows (128..143): row 128 = 1.0 for j<64, rest 0
    for (int idx = tid; idx < 16 * 72; idx += 256) {
        int r = idx / 72, k = idx % 72;
        Hls[128 + r][k] = (r == 0 && k < 64) ? (unsigned short)0x3F80u : (unsigned short)0u;
    }

    floatx4 acc[9];
    #pragma unroll
    for (int nt = 0; nt < 9; ++nt) acc[nt] = (floatx4){0.f, 0.f, 0.f, 0.f};

    union AFrag { unsigned int w[4]; bf16x8 v; };

    const int hf = tid >> 1;               // staging: thread -> H^T row
    const int jh = (tid & 1) * 32;

    for (int jt = 0; jt < 16; ++jt) {
        const int j0 = jt * 64;
        __syncthreads();                   // previous tile's Hls reads complete

        // issue H^T staging loads (land during frag build below)
        const unsigned short* hrow = hb + (size_t)hf * NN + j0 + jh;
        uint4 U0 = *reinterpret_cast<const uint4*>(hrow);
        uint4 U1 = *reinterpret_cast<const uint4*>(hrow + 8);
        uint4 U2 = *reinterpret_cast<const uint4*>(hrow + 16);
        uint4 U3 = *reinterpret_cast<const uint4*>(hrow + 24);

        // build A-fragments in registers (branchless)
        AFrag af[2];                       // [kh]
        #pragma unroll
        for (int kh = 0; kh < 2; ++kh) {
            const int jb = j0 + kh * 32 + kq;
            float4 eA = *reinterpret_cast<const float4*>(erp + jb);
            float4 eB = *reinterpret_cast<const float4*>(erp + jb + 4);
            float ee[8] = {eA.x, eA.y, eA.z, eA.w, eB.x, eB.y, eB.z, eB.w};
            float4 xA = *reinterpret_cast<const float4*>(xrp + jb);
            float4 xB = *reinterpret_cast<const float4*>(xrp + jb + 4);
            float xx[8] = {xA.x, xA.y, xA.z, xA.w, xB.x, xB.y, xB.z, xB.w};
            float a0[8];
            if (mode == 0) {
                float4 A0 = *reinterpret_cast<const float4*>(slab + (size_t)r0 * NN + jb);
                float4 A1 = *reinterpret_cast<const float4*>(slab + (size_t)r0 * NN + jb + 4);
                a0[0]=A0.x;a0[1]=A0.y;a0[2]=A0.z;a0[3]=A0.w;a0[4]=A1.x;a0[5]=A1.y;a0[6]=A1.z;a0[7]=A1.w;
            } else if (mode == 1) {
                float4 D0 = *reinterpret_cast<const float4*>(dvp + jb);
                float4 D1 = *reinterpret_cast<const float4*>(dvp + jb + 4);
                a0[0]=D0.x*gdv0;a0[1]=D0.y*gdv0;a0[2]=D0.z*gdv0;a0[3]=D0.w*gdv0;
                a0[4]=D1.x*gdv0;a0[5]=D1.y*gdv0;a0[6]=D1.z*gdv0;a0[7]=D1.w*gdv0;
            } else {
                #pragma unroll
                for (int g = 0; g < 8; ++g) {
                    const float* col = slab + (size_t)(jb + g) * NN;
                    a0[g] = col[r0];       // lanes of a quad read 16 consecutive i
                }
            }
            #pragma unroll
            for (int gp = 0; gp < 4; ++gp) {
                float q0[2];
                #pragma unroll
                for (int h = 0; h < 2; ++h) {
                    const int g = 2 * gp + h;
                    const float ez = 0.01f * ee[g];
                    q0[h] = fmaxf(Ei0 * xx[g] * a0[g], fmaf(a0[g], c0 + ez, 1.0f));
                }
                af[kh].w[gp] = pk2bf(q0[0], q0[1]);
            }
        }

        // commit H^T tile to LDS (loads have landed by now)
        *reinterpret_cast<uint4*>(&Hls[hf][jh])      = U0;
        *reinterpret_cast<uint4*>(&Hls[hf][jh + 8])  = U1;
        *reinterpret_cast<uint4*>(&Hls[hf][jh + 16]) = U2;
        *reinterpret_cast<uint4*>(&Hls[hf][jh + 24]) = U3;
        __syncthreads();

        // MFMA: 2 kh x 9 nt
        #pragma unroll
        for (int kh = 0; kh < 2; ++kh) {
            const int k0 = kh * 32 + kq;
            #pragma unroll
            for (int nt = 0; nt < 9; ++nt) {
                bf16x8 bfr = *reinterpret_cast<const bf16x8*>(&Hls[nt * 16 + lrow][k0]);
                acc[nt] = __builtin_amdgcn_mfma_f32_16x16x32_bf16(af[kh].v, bfr, acc[nt], 0, 0, 0);
            }
        }
    }

    // ---- epilogue: l from n-tile 8 (col 0), scale, atomic add ----
    if (lrow == 0) {
        #pragma unroll
        for (int r = 0; r < 4; ++r)
            lls[wv * 16 + quad * 4 + r] = acc[8][r];
    }
    __syncthreads();

    const float scale = (t >= 6) ? 0.5f : 1.0f;
    float* ob = out + ((size_t)b * NN + i0) * FF;
    #pragma unroll
    for (int r = 0; r < 4; ++r) {
        const int m = wv * 16 + quad * 4 + r;
        const float inv = scale / lls[m];
        #pragma unroll
        for (int nt = 0; nt < 8; ++nt)
            atomicAdd(&ob[(size_t)m * FF + nt * 16 + lrow], acc[nt][r] * inv);
    }
}

// ---------------------------------------------------------------------------
// K6: relu in place
// ---------------------------------------------------------------------------
__global__ __launch_bounds__(256) void k6_relu(float* __restrict__ out)
{
    const int gid = blockIdx.x * 256 + threadIdx.x;
    out[gid] = fmaxf(out[gid], 0.f);
}

extern "C" void kernel_launch(void* const* d_in, const int* in_sizes, int n_in,
                              void* d_out, int out_size, void* d_ws, size_t ws_size,
                              hipStream_t stream)
{
    const float* x         = (const float*)d_in[0];
    const float* adjs      = (const float*)d_in[1];
    const float* fc_w      = (const float*)d_in[2];
    const float* fc_b      = (const float*)d_in[3];
    const float* att_w     = (const float*)d_in[4];
    const float* att_b     = (const float*)d_in[5];
    const float* fwd_fc_w  = (const float*)d_in[6];
    const float* fwd_fc_b  = (const float*)d_in[7];
    const float* fwd_att_w = (const float*)d_in[8];
    const float* fwd_att_b = (const float*)d_in[9];
    const float* bwd_fc_w  = (const float*)d_in[10];
    const float* bwd_fc_b  = (const float*)d_in[11];
    const float* bwd_att_w = (const float*)d_in[12];
    const float* bwd_att_b = (const float*)d_in[13];
    const float* self_w    = (const float*)d_in[14];
    const float* self_b    = (const float*)d_in[15];
    const float* bias_in   = (const float*)d_in[16];
    float* out = (float*)d_out;

    char* ws = (char*)d_ws;
    unsigned short* H16T = (unsigned short*)(ws + H_OFF);
    float* el = (float*)(ws + EL_OFF);
    float* er = (float*)(ws + ER_OFF);
    float* dv = (float*)(ws + DV_OFF);
    float* FV = (float*)(ws + FV_OFF);
    float* FB = (float*)(ws + FB_OFF);
    float* xl = (float*)(ws + XL_OFF);
    float* xr = (float*)(ws + XR_OFF);

    // K0: folded attention vectors (128 rows, 24 real) + biases + diagonals
    k0_setup<<<224, 256, 0, stream>>>(adjs, fc_w, fc_b, att_w, att_b,
                                      fwd_att_w, fwd_att_b, bwd_att_w, bwd_att_b,
                                      FV, FB, dv);

    // K1: 14-channel projection GEMM, 128x128 tiles (ch0 -> out,
    // 1..12 -> H^T, 13 -> el/er/exp)
    k1_gemm<<<dim3(14, 64), 256, 0, stream>>>(
        x, fc_w, fc_b, fwd_fc_w, fwd_fc_b, bwd_fc_w, bwd_fc_b,
        self_w, self_b, bias_in, FV, FB, out, H16T, el, er, xl, xr);

    // K5: dense MFMA attention-apply, 64-row tiles (grid 1536 = 6 blocks/CU)
    k5_dense<<<BB * NT * 16, 256, 0, stream>>>(adjs, H16T, el, er, xl, xr, dv, out);

    // K6: relu
    k6_relu<<<out_size / 256, 256, 0, stream>>>(out);
}

// Round 14
// 480.407 us; speedup vs baseline: 1.0351x; 1.0351x over previous
//
#include <hip/hip_runtime.h>
#include <hip/hip_bf16.h>

typedef __bf16 bf16x8 __attribute__((ext_vector_type(8)));
typedef __bf16 bf16x4 __attribute__((ext_vector_type(4)));
typedef float floatx4 __attribute__((ext_vector_type(4)));

static constexpr int BB = 8;      // batch
static constexpr int NN = 1024;   // nodes
static constexpr int FF = 128;    // features
static constexpr int NT = 12;     // attention tasks: 0-5 rel, 6-8 fwd, 9-11 bwd

// workspace layout (bytes)
static constexpr size_t H_OFF  = 0;                                   // bf16 H^T [8][12][128][1024]
static constexpr size_t H_SZ   = (size_t)BB*NT*FF*NN*2;
static constexpr size_t EL_OFF = H_OFF + H_SZ;                        // f32 [96][1024]
static constexpr size_t EL_SZ  = (size_t)BB*NT*NN*4;
static constexpr size_t ER_OFF = EL_OFF + EL_SZ;                      // f32 [96][1024]
static constexpr size_t DV_OFF = ER_OFF + EL_SZ;                      // f32 [8][3][1024]
static constexpr size_t DV_SZ  = (size_t)BB*3*NN*4;
static constexpr size_t FV_OFF = DV_OFF + DV_SZ;                      // f32 folded [128][128] (rows 24+ zero)
static constexpr size_t FV_SZ  = (size_t)128*128*4;
static constexpr size_t FB_OFF = FV_OFF + FV_SZ;                      // f32 folded bias [128]
static constexpr size_t XL_OFF = FB_OFF + 512;                        // f32 exp(el) [96][1024]
static constexpr size_t XR_OFF = XL_OFF + EL_SZ;                      // f32 exp(er) [96][1024]

__device__ __forceinline__ unsigned short f2bf(float f) {
    union { float f; unsigned int i; } c; c.f = f;
    unsigned int r = (c.i + 0x7fffu + ((c.i >> 16) & 1u)) >> 16;   // RNE, finite inputs
    return (unsigned short)r;
}
// pack two positive floats to bf16x2 (round-half-up, 4 ops) — k5 hot path
__device__ __forceinline__ unsigned int pk2bf(float lo, float hi) {
    unsigned int il = __float_as_uint(lo) + 0x8000u;
    unsigned int ih = __float_as_uint(hi) + 0x8000u;
    return (il >> 16) | (ih & 0xffff0000u);
}

// ---------------------------------------------------------------------------
// K0: setup. Blocks 0..127: folded attention vectors FV[v][k] (v=2t+side,
// rows 24..127 zeroed) + folded biases FB[v]. Blocks 128..223: diag extract.
// ---------------------------------------------------------------------------
__global__ __launch_bounds__(256) void k0_setup(
    const float* __restrict__ adjs, const float* __restrict__ fc_w,
    const float* __restrict__ fc_b,
    const float* __restrict__ att_w, const float* __restrict__ att_b,
    const float* __restrict__ fwd_att_w, const float* __restrict__ fwd_att_b,
    const float* __restrict__ bwd_att_w, const float* __restrict__ bwd_att_b,
    float* __restrict__ FV, float* __restrict__ FB, float* __restrict__ DV)
{
    __shared__ float red[128];
    const int tid = threadIdx.x;
    const int bid = blockIdx.x;
    if (bid < 128) {
        const int v = bid;
        if (tid < 128) {
            float s = 0.f, bacc = 0.f;
            if (v < 24) {
                const int t = v >> 1, side = v & 1;
                const int hch = (t < 6) ? t : 5;
                const float* aw =
                    (t < 6) ? att_w + t * 256 :
                    (t < 9) ? fwd_att_w + (t - 6) * 256 : bwd_att_w + (t - 9) * 256;
                aw += side * 128;
                const float* W = fc_w + hch * 16384;
                for (int f = 0; f < 128; ++f) s += aw[f] * W[f * 128 + tid];
                bacc = fc_b[hch * 128 + tid] * aw[tid];
            }
            FV[v * 128 + tid] = s;
            red[tid] = bacc;
        }
        __syncthreads();
        if (tid == 0) {
            float s = 0.f;
            if (v < 24) {
                for (int i = 0; i < 128; ++i) s += red[i];
                if (v & 1) {
                    const int t = v >> 1;
                    s += (t < 6) ? att_b[t] : (t < 9) ? fwd_att_b[t - 6] : bwd_att_b[t - 9];
                }
            }
            FB[v] = s;
        }
    } else {
        const int gid = (bid - 128) * 256 + tid;   // (b*3+jj)*1024+n
        const int b   = gid / 3072;
        const int rem = gid % 3072;
        const int jj  = rem >> 10;
        const int n   = rem & 1023;
        DV[gid] = adjs[(((size_t)b * 9 + 3 + jj) * NN + n) * NN + n];
    }
}

// ---------------------------------------------------------------------------
// K1 v2: bf16 MFMA GEMM with 128-row x 128-col (full-channel) tiles.
// Grid (14, 64). ch0 -> d_out; ch 1..12 -> H^T bf16; ch13 -> el/er/exp.
// ---------------------------------------------------------------------------
__global__ __launch_bounds__(256) void k1_gemm(
    const float* __restrict__ x,
    const float* __restrict__ fc_w, const float* __restrict__ fc_b,
    const float* __restrict__ fwd_fc_w, const float* __restrict__ fwd_fc_b,
    const float* __restrict__ bwd_fc_w, const float* __restrict__ bwd_fc_b,
    const float* __restrict__ self_w, const float* __restrict__ self_b,
    const float* __restrict__ bias_in,
    const float* __restrict__ FV, const float* __restrict__ FB,
    float* __restrict__ out, unsigned short* __restrict__ H16T,
    float* __restrict__ el, float* __restrict__ er,
    float* __restrict__ xl, float* __restrict__ xr)
{
    __shared__ __align__(16) char smem[52224];
    __bf16* Als = (__bf16*)smem;                  // [128][136] = 34816 B
    __bf16* Bls = (__bf16*)(smem + 34816);        // [64][136]  = 17408 B

    const int tid = threadIdx.x;
    const int m0  = blockIdx.y * 128;      // global row (b*1024+n)
    const int ch  = blockIdx.x;            // channel 0..13

    const float* wsel; const float* bsel;
    if (ch == 0)       { wsel = self_w;                    bsel = self_b; }
    else if (ch <= 6)  { wsel = fc_w     + (ch-1)*16384;   bsel = fc_b     + (ch-1)*128; }
    else if (ch <= 9)  { wsel = fwd_fc_w + (ch-7)*16384;   bsel = fwd_fc_b + (ch-7)*128; }
    else if (ch <= 12) { wsel = bwd_fc_w + (ch-10)*16384;  bsel = bwd_fc_b + (ch-10)*128; }
    else               { wsel = FV;                        bsel = FB; }

    // stage A: 128 rows x 128 k (fp32 -> bf16)
    for (int it = 0; it < 16; ++it) {
        int idx = tid + it * 256;          // 4096 float4 slots
        int r  = idx >> 5;
        int c4 = idx & 31;
        float4 va = *reinterpret_cast<const float4*>(x + (size_t)(m0 + r) * 128 + c4 * 4);
        *reinterpret_cast<bf16x4*>(&Als[r * 136 + c4 * 4]) =
            (bf16x4){(__bf16)va.x, (__bf16)va.y, (__bf16)va.z, (__bf16)va.w};
    }

    const int wv   = tid >> 6;
    const int lane = tid & 63;
    const int lrow = lane & 15;
    const int quad = lane >> 4;

    floatx4 acc[2][8];
    #pragma unroll
    for (int mt = 0; mt < 2; ++mt)
        #pragma unroll
        for (int c = 0; c < 8; ++c) acc[mt][c] = (floatx4){0.f, 0.f, 0.f, 0.f};

    for (int half = 0; half < 2; ++half) {
        __syncthreads();   // half 0: A staged; half 1: previous B reads done
        for (int it = 0; it < 8; ++it) {
            int idx = tid + it * 256;      // 2048 float4 slots
            int r  = idx >> 5;
            int c4 = idx & 31;
            float4 vb = *reinterpret_cast<const float4*>(
                wsel + (size_t)(half * 64 + r) * 128 + c4 * 4);
            *reinterpret_cast<bf16x4*>(&Bls[r * 136 + c4 * 4]) =
                (bf16x4){(__bf16)vb.x, (__bf16)vb.y, (__bf16)vb.z, (__bf16)vb.w};
        }
        __syncthreads();

        #pragma unroll
        for (int kk = 0; kk < 4; ++kk) {
            const int k0 = kk * 32 + quad * 8;
            bf16x8 a0 = *reinterpret_cast<const bf16x8*>(&Als[(wv * 32 + lrow) * 136 + k0]);
            bf16x8 a1 = *reinterpret_cast<const bf16x8*>(&Als[(wv * 32 + 16 + lrow) * 136 + k0]);
            #pragma unroll
            for (int c = 0; c < 4; ++c) {
                bf16x8 bfr = *reinterpret_cast<const bf16x8*>(&Bls[(c * 16 + lrow) * 136 + k0]);
                acc[0][half * 4 + c] = __builtin_amdgcn_mfma_f32_16x16x32_bf16(a0, bfr, acc[0][half * 4 + c], 0, 0, 0);
                acc[1][half * 4 + c] = __builtin_amdgcn_mfma_f32_16x16x32_bf16(a1, bfr, acc[1][half * 4 + c], 0, 0, 0);
            }
        }
    }

    // ---- epilogue (reuses smem) ----
    __syncthreads();   // all MFMA LDS reads done

    const int b  = m0 >> 10;
    const int nb = m0 & 1023;

    if (ch >= 1 && ch <= 12) {
        // pack bf16 row-pairs into uint grid [fcol 0..127][rowpair 0..63], stride 65
        unsigned int* SDH = (unsigned int*)smem;   // 128*65*4 = 33280 B
        #pragma unroll
        for (int c = 0; c < 8; ++c) {
            const int fl = c * 16 + lrow;
            const float bv = bsel[fl];
            #pragma unroll
            for (int mt = 0; mt < 2; ++mt) {
                #pragma unroll
                for (int p = 0; p < 2; ++p) {
                    unsigned int pk = (unsigned int)f2bf(acc[mt][c][2*p] + bv)
                                    | ((unsigned int)f2bf(acc[mt][c][2*p+1] + bv) << 16);
                    SDH[fl * 65 + wv * 16 + mt * 8 + quad * 2 + p] = pk;
                }
            }
        }
        __syncthreads();
        const int f  = tid >> 1;               // 0..127
        const int ns = (tid & 1) * 64;         // shorts
        unsigned short* dst = H16T + (((size_t)b * NT + (ch - 1)) * FF + f) * NN + nb + ns;
        #pragma unroll
        for (int g = 0; g < 8; ++g) {
            const unsigned int* src = &SDH[f * 65 + ns / 2 + g * 4];
            *reinterpret_cast<uint4*>(dst + g * 8) = (uint4){src[0], src[1], src[2], src[3]};
        }
    } else if (ch == 0) {
        // two 64-col passes through SD [128][68] f32 (34816 B)
        float* SD = (float*)smem;
        #pragma unroll
        for (int half = 0; half < 2; ++half) {
            if (half) __syncthreads();
            #pragma unroll
            for (int c = 0; c < 4; ++c) {
                const int fl = c * 16 + lrow;
                const float bv = bsel[half * 64 + fl] + bias_in[half * 64 + fl];
                #pragma unroll
                for (int mt = 0; mt < 2; ++mt)
                    #pragma unroll
                    for (int r = 0; r < 4; ++r)
                        SD[(wv * 32 + mt * 16 + quad * 4 + r) * 68 + fl] = acc[mt][half * 4 + c][r] + bv;
            }
            __syncthreads();
            const int n  = tid >> 1;           // 0..127
            const int fs = (tid & 1) * 32;
            float* dst = out + (size_t)(m0 + n) * 128 + half * 64 + fs;
            #pragma unroll
            for (int g = 0; g < 8; ++g)
                reinterpret_cast<float4*>(dst)[g] =
                    *reinterpret_cast<const float4*>(&SD[n * 68 + fs + 4 * g]);
        }
    } else {
        // ch 13: only cols 0..23 meaningful -> single half-0 pass
        float* SD = (float*)smem;
        #pragma unroll
        for (int c = 0; c < 4; ++c) {
            const int fl = c * 16 + lrow;
            const float bv = bsel[fl];
            #pragma unroll
            for (int mt = 0; mt < 2; ++mt)
                #pragma unroll
                for (int r = 0; r < 4; ++r)
                    SD[(wv * 32 + mt * 16 + quad * 4 + r) * 68 + fl] = acc[mt][c][r] + bv;
        }
        __syncthreads();
        const int n  = tid >> 1;               // 0..127
        const int c3 = tid & 1;
        #pragma unroll
        for (int tt = 0; tt < 6; ++tt) {
            const int t = c3 * 6 + tt;
            const float ev = SD[n * 68 + 2 * t];
            const float rv = SD[n * 68 + 2 * t + 1];
            const size_t o = ((size_t)b * NT + t) * NN + nb + n;
            el[o] = ev;  xl[o] = __expf(ev);
            er[o] = rv;  xr[o] = __expf(rv);
        }
    }
}

// ---------------------------------------------------------------------------
// K5-dense (R9-proven, best measured): 128-row tiles, single-buffer LDS
// H-staging, register A-frags, branchless
//  q = max( exp(el_i)*exp(er_j)*a , fma(a, 0.01*(el_i+er_j), 1) ), a in {0,1},
// l via MFMA ones-column. Variants tested and rejected: dbuf (R11 +10us),
// no-LDS (R10 +76us), 64-row/2x grid (R13 +15us), bitmask adj (R7 +148us).
// ---------------------------------------------------------------------------
__global__ __launch_bounds__(256) void k5_dense(
    const float* __restrict__ adjs, const unsigned short* __restrict__ H16T,
    const float* __restrict__ el, const float* __restrict__ er,
    const float* __restrict__ xl, const float* __restrict__ xr,
    const float* __restrict__ dv, float* __restrict__ out)
{
    __shared__ __align__(16) unsigned short Hls[144][72];  // [f][j], rows 128+ = ones
    __shared__ float lls[128];

    const int tid  = threadIdx.x;
    const int lane = tid & 63;
    const int wv   = tid >> 6;
    const int bi   = blockIdx.x;
    const int b    = bi & 7;               // batch -> XCD
    const int q    = bi >> 3;              // 0..95
    const int tq   = q >> 3;               // 0..11 schedule slot
    // schedule {0..5,6,9,7,10,8,11}: fwd/bwd of same slab adjacent for L2 reuse
    const int t    = (tq < 6) ? tq : (6 + (tq - 6) / 2 + ((tq - 6) & 1) * 3);
    const int i0   = (q & 7) * 128;
    const int bt   = b * NT + t;

    const unsigned short* hb = H16T + (size_t)bt * FF * NN;
    const float* elp = el + (size_t)bt * NN;
    const float* erp = er + (size_t)bt * NN;
    const float* xrp = xr + (size_t)bt * NN;
    const float* dvp = dv + (size_t)(b * 3 + ((t - 3) % 3 + 3) % 3) * NN;

    int mode; const float* slab = nullptr;
    if (t < 3)       { mode = 0; slab = adjs + ((size_t)b * 9 + t) * (size_t)NN * NN; }
    else if (t < 6)  { mode = 1; }
    else if (t < 9)  { mode = 0; slab = adjs + ((size_t)b * 9 + t) * (size_t)NN * NN; }
    else             { mode = 2; slab = adjs + ((size_t)b * 9 + (t - 3)) * (size_t)NN * NN; }

    const int lrow = lane & 15;
    const int quad = lane >> 4;
    const int kq   = quad * 8;
    const int r0   = i0 + wv * 32 + lrow;
    const int r1   = r0 + 16;

    const float c0  = 0.01f * elp[r0];     // negative-branch linear term
    const float c1  = 0.01f * elp[r1];
    const float Ei0 = xl[(size_t)bt * NN + r0];
    const float Ei1 = xl[(size_t)bt * NN + r1];
    float gdv0 = 1.f, gdv1 = 1.f;
    if (mode == 1) { gdv0 = dvp[r0]; gdv1 = dvp[r1]; }   // exact 0/1

    // ones rows (128..143): row 128 = 1.0 for j<64, rest 0
    for (int idx = tid; idx < 16 * 72; idx += 256) {
        int r = idx / 72, k = idx % 72;
        Hls[128 + r][k] = (r == 0 && k < 64) ? (unsigned short)0x3F80u : (unsigned short)0u;
    }

    floatx4 acc[2][9];
    #pragma unroll
    for (int mt = 0; mt < 2; ++mt)
        #pragma unroll
        for (int nt = 0; nt < 9; ++nt) acc[mt][nt] = (floatx4){0.f, 0.f, 0.f, 0.f};

    union AFrag { unsigned int w[4]; bf16x8 v; };

    const int hf = tid >> 1;               // staging: thread -> H^T row
    const int jh = (tid & 1) * 32;

    for (int jt = 0; jt < 16; ++jt) {
        const int j0 = jt * 64;
        __syncthreads();                   // previous tile's Hls reads complete

        // issue H^T staging loads (land during frag build below)
        const unsigned short* hrow = hb + (size_t)hf * NN + j0 + jh;
        uint4 U0 = *reinterpret_cast<const uint4*>(hrow);
        uint4 U1 = *reinterpret_cast<const uint4*>(hrow + 8);
        uint4 U2 = *reinterpret_cast<const uint4*>(hrow + 16);
        uint4 U3 = *reinterpret_cast<const uint4*>(hrow + 24);

        // build A-fragments in registers (branchless)
        AFrag af[2][2];                    // [mt][kh]
        #pragma unroll
        for (int kh = 0; kh < 2; ++kh) {
            const int jb = j0 + kh * 32 + kq;
            float4 eA = *reinterpret_cast<const float4*>(erp + jb);
            float4 eB = *reinterpret_cast<const float4*>(erp + jb + 4);
            float ee[8] = {eA.x, eA.y, eA.z, eA.w, eB.x, eB.y, eB.z, eB.w};
            float4 xA = *reinterpret_cast<const float4*>(xrp + jb);
            float4 xB = *reinterpret_cast<const float4*>(xrp + jb + 4);
            float xx[8] = {xA.x, xA.y, xA.z, xA.w, xB.x, xB.y, xB.z, xB.w};
            float a0[8], a1[8];
            if (mode == 0) {
                float4 A0 = *reinterpret_cast<const float4*>(slab + (size_t)r0 * NN + jb);
                float4 A1 = *reinterpret_cast<const float4*>(slab + (size_t)r0 * NN + jb + 4);
                float4 B0 = *reinterpret_cast<const float4*>(slab + (size_t)r1 * NN + jb);
                float4 B1 = *reinterpret_cast<const float4*>(slab + (size_t)r1 * NN + jb + 4);
                a0[0]=A0.x;a0[1]=A0.y;a0[2]=A0.z;a0[3]=A0.w;a0[4]=A1.x;a0[5]=A1.y;a0[6]=A1.z;a0[7]=A1.w;
                a1[0]=B0.x;a1[1]=B0.y;a1[2]=B0.z;a1[3]=B0.w;a1[4]=B1.x;a1[5]=B1.y;a1[6]=B1.z;a1[7]=B1.w;
            } else if (mode == 1) {
                float4 D0 = *reinterpret_cast<const float4*>(dvp + jb);
                float4 D1 = *reinterpret_cast<const float4*>(dvp + jb + 4);
                float d8[8] = {D0.x,D0.y,D0.z,D0.w,D1.x,D1.y,D1.z,D1.w};
                #pragma unroll
                for (int g = 0; g < 8; ++g) { a0[g] = d8[g] * gdv0; a1[g] = d8[g] * gdv1; }
            } else {
                #pragma unroll
                for (int g = 0; g < 8; ++g) {
                    const float* col = slab + (size_t)(jb + g) * NN;
                    a0[g] = col[r0];       // lanes of a quad read 16 consecutive i
                    a1[g] = col[r1];
                }
            }
            #pragma unroll
            for (int gp = 0; gp < 4; ++gp) {
                float q0[2], q1[2];
                #pragma unroll
                for (int h = 0; h < 2; ++h) {
                    const int g = 2 * gp + h;
                    const float ez = 0.01f * ee[g];
                    q0[h] = fmaxf(Ei0 * xx[g] * a0[g], fmaf(a0[g], c0 + ez, 1.0f));
                    q1[h] = fmaxf(Ei1 * xx[g] * a1[g], fmaf(a1[g], c1 + ez, 1.0f));
                }
                af[0][kh].w[gp] = pk2bf(q0[0], q0[1]);
                af[1][kh].w[gp] = pk2bf(q1[0], q1[1]);
            }
        }

        // commit H^T tile to LDS (loads have landed by now)
        *reinterpret_cast<uint4*>(&Hls[hf][jh])      = U0;
        *reinterpret_cast<uint4*>(&Hls[hf][jh + 8])  = U1;
        *reinterpret_cast<uint4*>(&Hls[hf][jh + 16]) = U2;
        *reinterpret_cast<uint4*>(&Hls[hf][jh + 24]) = U3;
        __syncthreads();

        // MFMA: 2 kh x 9 nt x 2 mt
        #pragma unroll
        for (int kh = 0; kh < 2; ++kh) {
            const int k0 = kh * 32 + kq;
            #pragma unroll
            for (int nt = 0; nt < 9; ++nt) {
                bf16x8 bfr = *reinterpret_cast<const bf16x8*>(&Hls[nt * 16 + lrow][k0]);
                acc[0][nt] = __builtin_amdgcn_mfma_f32_16x16x32_bf16(af[0][kh].v, bfr, acc[0][nt], 0, 0, 0);
                acc[1][nt] = __builtin_amdgcn_mfma_f32_16x16x32_bf16(af[1][kh].v, bfr, acc[1][nt], 0, 0, 0);
            }
        }
    }

    // ---- epilogue: l from n-tile 8 (col 0), scale, atomic add ----
    if (lrow == 0) {
        #pragma unroll
        for (int mt = 0; mt < 2; ++mt)
            #pragma unroll
            for (int r = 0; r < 4; ++r)
                lls[wv * 32 + mt * 16 + quad * 4 + r] = acc[mt][8][r];
    }
    __syncthreads();

    const float scale = (t >= 6) ? 0.5f : 1.0f;
    float* ob = out + ((size_t)b * NN + i0) * FF;
    #pragma unroll
    for (int mt = 0; mt < 2; ++mt) {
        #pragma unroll
        for (int r = 0; r < 4; ++r) {
            const int m = wv * 32 + mt * 16 + quad * 4 + r;
            const float inv = scale / lls[m];
            #pragma unroll
            for (int nt = 0; nt < 8; ++nt)
                atomicAdd(&ob[(size_t)m * FF + nt * 16 + lrow], acc[mt][nt][r] * inv);
        }
    }
}

// ---------------------------------------------------------------------------
// K6: relu in place
// ---------------------------------------------------------------------------
__global__ __launch_bounds__(256) void k6_relu(float* __restrict__ out)
{
    const int gid = blockIdx.x * 256 + threadIdx.x;
    out[gid] = fmaxf(out[gid], 0.f);
}

extern "C" void kernel_launch(void* const* d_in, const int* in_sizes, int n_in,
                              void* d_out, int out_size, void* d_ws, size_t ws_size,
                              hipStream_t stream)
{
    const float* x         = (const float*)d_in[0];
    const float* adjs      = (const float*)d_in[1];
    const float* fc_w      = (const float*)d_in[2];
    const float* fc_b      = (const float*)d_in[3];
    const float* att_w     = (const float*)d_in[4];
    const float* att_b     = (const float*)d_in[5];
    const float* fwd_fc_w  = (const float*)d_in[6];
    const float* fwd_fc_b  = (const float*)d_in[7];
    const float* fwd_att_w = (const float*)d_in[8];
    const float* fwd_att_b = (const float*)d_in[9];
    const float* bwd_fc_w  = (const float*)d_in[10];
    const float* bwd_fc_b  = (const float*)d_in[11];
    const float* bwd_att_w = (const float*)d_in[12];
    const float* bwd_att_b = (const float*)d_in[13];
    const float* self_w    = (const float*)d_in[14];
    const float* self_b    = (const float*)d_in[15];
    const float* bias_in   = (const float*)d_in[16];
    float* out = (float*)d_out;

    char* ws = (char*)d_ws;
    unsigned short* H16T = (unsigned short*)(ws + H_OFF);
    float* el = (float*)(ws + EL_OFF);
    float* er = (float*)(ws + ER_OFF);
    float* dv = (float*)(ws + DV_OFF);
    float* FV = (float*)(ws + FV_OFF);
    float* FB = (float*)(ws + FB_OFF);
    float* xl = (float*)(ws + XL_OFF);
    float* xr = (float*)(ws + XR_OFF);

    // K0: folded attention vectors (128 rows, 24 real) + biases + diagonals
    k0_setup<<<224, 256, 0, stream>>>(adjs, fc_w, fc_b, att_w, att_b,
                                      fwd_att_w, fwd_att_b, bwd_att_w, bwd_att_b,
                                      FV, FB, dv);

    // K1: 14-channel projection GEMM, 128x128 tiles (ch0 -> out,
    // 1..12 -> H^T, 13 -> el/er/exp)
    k1_gemm<<<dim3(14, 64), 256, 0, stream>>>(
        x, fc_w, fc_b, fwd_fc_w, fwd_fc_b, bwd_fc_w, bwd_fc_b,
        self_w, self_b, bias_in, FV, FB, out, H16T, el, er, xl, xr);

    // K5: dense MFMA attention-apply (best-measured config)
    k5_dense<<<BB * NT * 8, 256, 0, stream>>>(adjs, H16T, el, er, xl, xr, dv, out);

    // K6: relu
    k6_relu<<<out_size / 256, 256, 0, stream>>>(out);
}